// Round 1
// baseline (1084.406 us; speedup 1.0000x reference)
//
#include <hip/hip_runtime.h>

#define N_NODES 4096
#define M_EDGES 4096
#define NNZ_K   262144
#define NCH     4
#define DIM     128
#define KDIM    512               // NCH*DIM
#define NM      (N_NODES * M_EDGES)
#define NUM_ADD 26214             // max(1, int(0.1*NNZ))
#define NBINS   65536
#define CAP     65536

// ---- workspace layout (byte offsets) ----
#define EXD_OFF   0ull                 // double[M*D]      4 MB
#define AFC_OFF   4194304ull           // float[N*512]     8 MB
#define BFC_OFF   12582912ull          // float[M*512]     8 MB
#define CNT_OFF   20971520ull          // int[4096]
#define OFFS_OFF  20987904ull          // int[4097]
#define CUR_OFF   21004320ull          // int[4096]
#define BKT_OFF   21020704ull          // int[NNZ]         1 MB
#define HIST_OFF  22069280ull          // int[65536]
#define SCL_OFF   22331424ull          // int[16]  {bstar, G1, ncand}
#define CVAL_OFF  22331488ull          // double[CAP]
#define CIDX_OFF  22855776ull          // int[CAP]

__device__ __forceinline__ int bin_of(float s) {
    int b = (int)floorf((s + 1.0f) * 32768.0f);
    return min(max(b, 0), NBINS - 1);
}

__device__ __forceinline__ float st_mask(float p, float e) {
    float logit = logf(e) - logf(1.0f - e) + logf(p + 1e-8f) - logf(1.0f - p + 1e-8f);
    float soft  = 1.0f / (1.0f + expf(-2.0f * logit));   // sigmoid(logit/TEMP), TEMP=0.5
    float hard  = (soft > 0.5f) ? 1.0f : 0.0f;
    return (hard - soft) + soft;                          // straight-through forward
}

// ---- 1. per-edge counts ----
__global__ void k_count(const int* __restrict__ E, int* __restrict__ cnt) {
    int k = blockIdx.x * 256 + threadIdx.x;
    if (k < NNZ_K) atomicAdd(&cnt[E[k]], 1);
}

// ---- 2. exclusive scan over 4096 counts ----
__global__ __launch_bounds__(256) void k_scan(const int* __restrict__ cnt, int* __restrict__ offs) {
    __shared__ int part[256];
    int t = threadIdx.x;
    int loc[16]; int s = 0;
    for (int j = 0; j < 16; ++j) { loc[j] = cnt[t * 16 + j]; s += loc[j]; }
    part[t] = s;
    __syncthreads();
    if (t == 0) { int acc = 0; for (int i = 0; i < 256; ++i) { int v = part[i]; part[i] = acc; acc += v; } }
    __syncthreads();
    int acc = part[t];
    for (int j = 0; j < 16; ++j) { offs[t * 16 + j] = acc; acc += loc[j]; }
    if (t == 255) offs[4096] = acc;
}

// ---- 3. bucket fill (order nondeterministic; fixed by sort in next kernel) ----
__global__ void k_fill(const int* __restrict__ E, const int* __restrict__ offs,
                       int* __restrict__ cur, int* __restrict__ bkt) {
    int k = blockIdx.x * 256 + threadIdx.x;
    if (k < NNZ_K) {
        int e = E[k];
        int pos = atomicAdd(&cur[e], 1);
        bkt[offs[e] + pos] = k;
    }
}

// ---- 4. deterministic scatter-mean: sort bucket by k, fp64 accumulate ----
__global__ __launch_bounds__(128) void k_edge_mean(
        const int* __restrict__ Vv, const int* __restrict__ cnt,
        const int* __restrict__ offs, const int* __restrict__ bkt,
        const float* __restrict__ X, double* __restrict__ eXd) {
    __shared__ int sk[1024];
    __shared__ int sv[1024];
    int m = blockIdx.x;
    int c = cnt[m]; if (c > 1024) c = 1024;
    int off = offs[m];
    for (int t = threadIdx.x; t < c; t += 128) sk[t] = bkt[off + t];
    __syncthreads();
    for (int t = threadIdx.x; t < c; t += 128) {   // rank sort (keys distinct)
        int key = sk[t]; int r = 0;
        for (int j = 0; j < c; ++j) r += (sk[j] < key);
        sv[r] = Vv[key];
    }
    __syncthreads();
    int d = threadIdx.x;
    double s = 0.0;
    for (int j = 0; j < c; ++j) s += (double)X[sv[j] * DIM + d];
    eXd[m * DIM + d] = s / (double)(c > 1 ? c : 1);
}

// ---- 5. per-channel L2-normalized features (fp64 internal, fp32 out) ----
template <typename T>
__global__ __launch_bounds__(128) void k_fc(const T* __restrict__ in,
                                            const float* __restrict__ w,
                                            float* __restrict__ out) {
    __shared__ double red[128];
    int n = blockIdx.x, d = threadIdx.x;
    double x = (double)in[n * DIM + d];
    for (int c = 0; c < NCH; ++c) {
        double v = x * (double)w[c * DIM + d];
        red[d] = v * v;
        __syncthreads();
        for (int s = 64; s > 0; s >>= 1) { if (d < s) red[d] += red[d + s]; __syncthreads(); }
        double denom = fmax(sqrt(red[0]), 1e-12);
        __syncthreads();
        out[n * KDIM + c * DIM + d] = (float)(v / denom);
    }
}

// ---- 6. fp32 GEMM: S = 0.25 * A(N,512) * B(M,512)^T -> d_out ----
#define BKK 32
__global__ __launch_bounds__(256) void k_gemm(const float* __restrict__ A,
                                              const float* __restrict__ B,
                                              float* __restrict__ S) {
    __shared__ float As[BKK][68];
    __shared__ float Bs[BKK][68];
    int row0 = blockIdx.y * 64, col0 = blockIdx.x * 64;
    int tid = threadIdx.x;
    int tx = tid & 15, ty = tid >> 4;
    int lr = tid >> 3;            // 0..31
    int lk = (tid & 7) * 4;       // 0,4,...,28
    float acc[4][4] = {};
    for (int k0 = 0; k0 < KDIM; k0 += BKK) {
        float4 a0 = *(const float4*)&A[(size_t)(row0 + lr) * KDIM + k0 + lk];
        float4 a1 = *(const float4*)&A[(size_t)(row0 + lr + 32) * KDIM + k0 + lk];
        float4 b0 = *(const float4*)&B[(size_t)(col0 + lr) * KDIM + k0 + lk];
        float4 b1 = *(const float4*)&B[(size_t)(col0 + lr + 32) * KDIM + k0 + lk];
        __syncthreads();
        As[lk + 0][lr] = a0.x; As[lk + 1][lr] = a0.y; As[lk + 2][lr] = a0.z; As[lk + 3][lr] = a0.w;
        As[lk + 0][lr + 32] = a1.x; As[lk + 1][lr + 32] = a1.y; As[lk + 2][lr + 32] = a1.z; As[lk + 3][lr + 32] = a1.w;
        Bs[lk + 0][lr] = b0.x; Bs[lk + 1][lr] = b0.y; Bs[lk + 2][lr] = b0.z; Bs[lk + 3][lr] = b0.w;
        Bs[lk + 0][lr + 32] = b1.x; Bs[lk + 1][lr + 32] = b1.y; Bs[lk + 2][lr + 32] = b1.z; Bs[lk + 3][lr + 32] = b1.w;
        __syncthreads();
        #pragma unroll
        for (int kk = 0; kk < BKK; ++kk) {
            float4 av = *(const float4*)&As[kk][ty * 4];
            float4 bv = *(const float4*)&Bs[kk][tx * 4];
            float a4[4] = {av.x, av.y, av.z, av.w};
            float b4[4] = {bv.x, bv.y, bv.z, bv.w};
            #pragma unroll
            for (int i = 0; i < 4; ++i)
                #pragma unroll
                for (int j = 0; j < 4; ++j)
                    acc[i][j] += a4[i] * b4[j];
        }
    }
    #pragma unroll
    for (int i = 0; i < 4; ++i)
        #pragma unroll
        for (int j = 0; j < 4; ++j)
            S[(size_t)(row0 + ty * 4 + i) * M_EDGES + (col0 + tx * 4 + j)] = 0.25f * acc[i][j];
}

// ---- 7. mask existing incidences ----
__global__ void k_mask(const int* __restrict__ Vv, const int* __restrict__ E, float* __restrict__ S) {
    int k = blockIdx.x * 256 + threadIdx.x;
    if (k < NNZ_K) S[(size_t)Vv[k] * M_EDGES + E[k]] = -1e30f;
}

// ---- 8. 65536-bin histogram of S ----
__global__ void k_hist(const float* __restrict__ S, int* __restrict__ hist) {
    int idx = blockIdx.x * 256 + threadIdx.x;
    float s = S[idx];
    if (s > -2.0f) atomicAdd(&hist[bin_of(s)], 1);
}

// ---- 9. find cutoff bin b* and G1 = count of bins >= b*+2 ----
__global__ __launch_bounds__(1024) void k_findcut(const int* __restrict__ hist, int* __restrict__ scl) {
    __shared__ int chunk[1024];
    int t = threadIdx.x;
    int s = 0;
    for (int j = 0; j < 64; ++j) s += hist[t * 64 + j];
    chunk[t] = s;
    __syncthreads();
    if (t == 0) { int acc = 0; for (int i = 1023; i >= 0; --i) { int v = chunk[i]; chunk[i] = acc; acc += v; } }
    __syncthreads();
    int run = chunk[t];                 // elements strictly above this chunk
    for (int j = 63; j >= 0; --j) {
        int h = hist[t * 64 + j];
        run += h;
        if (run >= NUM_ADD && run - h < NUM_ADD) {
            int bstar = t * 64 + j;
            int g0 = run - h;           // count in bins > bstar
            int h1 = (bstar + 1 < NBINS) ? hist[bstar + 1] : 0;
            scl[0] = bstar;
            scl[1] = g0 - h1;           // G1: certainly-selected count (bins >= bstar+2)
        }
    }
}

// ---- 10. collect boundary-band candidates (bins b*-1..b*+1) ----
__global__ void k_collect(const float* __restrict__ S, int* __restrict__ scl, int* __restrict__ cidx) {
    int idx = blockIdx.x * 256 + threadIdx.x;
    float s = S[idx];
    if (s > -2.0f) {
        int b = bin_of(s);
        int bs = scl[0];
        if (b >= bs - 1 && b <= bs + 1) {
            int slot = atomicAdd(&scl[2], 1);
            if (slot < CAP) cidx[slot] = idx;
        }
    }
}

// ---- 11. elementwise output for everything outside the band ----
__global__ void k_final(float* __restrict__ S_out, const float* __restrict__ H,
                        const float* __restrict__ prob, const float* __restrict__ eps,
                        const int* __restrict__ scl) {
    int idx = blockIdx.x * 256 + threadIdx.x;
    float s = S_out[idx];
    int bs = scl[0];
    float add = (s > -2.0f && bin_of(s) > bs + 1) ? 1.0f : 0.0f;
    S_out[idx] = (H[idx] + add) * st_mask(prob[idx], eps[idx]);
}

// ---- 12. fp64 re-rank of band candidates; fix up selected ones ----
__global__ __launch_bounds__(256) void k_fixup(
        const int* __restrict__ scl, const int* __restrict__ cidx, double* __restrict__ cval,
        const float* __restrict__ X, const double* __restrict__ eXd, const float* __restrict__ cw,
        const float* __restrict__ H, const float* __restrict__ prob, const float* __restrict__ eps,
        float* __restrict__ out) {
    int nc = scl[2]; if (nc > CAP) nc = CAP;
    int G1 = scl[1];
    int t = threadIdx.x;
    for (int i = t; i < nc; i += 256) {
        int idx = cidx[i];
        int n = idx >> 12, m = idx & (M_EDGES - 1);
        double acc = 0.0;
        for (int c = 0; c < NCH; ++c) {
            double dn = 0.0, de = 0.0, dt = 0.0;
            for (int d = 0; d < DIM; ++d) {
                double w  = (double)cw[c * DIM + d];
                double xn = (double)X[n * DIM + d] * w;
                double xe = eXd[m * DIM + d] * w;
                dn += xn * xn; de += xe * xe; dt += xn * xe;
            }
            acc += dt / (fmax(sqrt(dn), 1e-12) * fmax(sqrt(de), 1e-12));
        }
        cval[i] = acc * 0.25;
    }
    __syncthreads();
    for (int i = t; i < nc; i += 256) {
        double v = cval[i]; int idx = cidx[i];
        int rank = G1;
        for (int j = 0; j < nc; ++j) {
            double u = cval[j]; int id2 = cidx[j];
            rank += (u > v || (u == v && id2 < idx)) ? 1 : 0;
        }
        if (rank < NUM_ADD)
            out[idx] = (H[idx] + 1.0f) * st_mask(prob[idx], eps[idx]);
    }
}

extern "C" void kernel_launch(void* const* d_in, const int* in_sizes, int n_in,
                              void* d_out, int out_size, void* d_ws, size_t ws_size,
                              hipStream_t stream) {
    const float* X    = (const float*)d_in[0];
    const float* H    = (const float*)d_in[1];
    const int*   Vv   = (const int*)d_in[2];
    const int*   E    = (const int*)d_in[3];
    const float* prob = (const float*)d_in[4];
    const float* cw   = (const float*)d_in[5];
    const float* eps  = (const float*)d_in[6];
    float* out = (float*)d_out;
    char*  ws  = (char*)d_ws;

    double* eXd  = (double*)(ws + EXD_OFF);
    float*  Afc  = (float*)(ws + AFC_OFF);
    float*  Bfc  = (float*)(ws + BFC_OFF);
    int*    cnt  = (int*)(ws + CNT_OFF);
    int*    offs = (int*)(ws + OFFS_OFF);
    int*    cur  = (int*)(ws + CUR_OFF);
    int*    bkt  = (int*)(ws + BKT_OFF);
    int*    hist = (int*)(ws + HIST_OFF);
    int*    scl  = (int*)(ws + SCL_OFF);
    double* cval = (double*)(ws + CVAL_OFF);
    int*    cidx = (int*)(ws + CIDX_OFF);

    hipMemsetAsync(ws + CNT_OFF, 0, (size_t)(SCL_OFF + 64 - CNT_OFF), stream);

    k_count<<<NNZ_K / 256, 256, 0, stream>>>(E, cnt);
    k_scan<<<1, 256, 0, stream>>>(cnt, offs);
    k_fill<<<NNZ_K / 256, 256, 0, stream>>>(E, offs, cur, bkt);
    k_edge_mean<<<M_EDGES, 128, 0, stream>>>(Vv, cnt, offs, bkt, X, eXd);
    k_fc<float><<<N_NODES, 128, 0, stream>>>(X, cw, Afc);
    k_fc<double><<<M_EDGES, 128, 0, stream>>>(eXd, cw, Bfc);
    dim3 gg(M_EDGES / 64, N_NODES / 64);
    k_gemm<<<gg, 256, 0, stream>>>(Afc, Bfc, out);
    k_mask<<<NNZ_K / 256, 256, 0, stream>>>(Vv, E, out);
    k_hist<<<NM / 256, 256, 0, stream>>>(out, hist);
    k_findcut<<<1, 1024, 0, stream>>>(hist, scl);
    k_collect<<<NM / 256, 256, 0, stream>>>(out, scl, cidx);
    k_final<<<NM / 256, 256, 0, stream>>>(out, H, prob, eps, scl);
    k_fixup<<<1, 256, 0, stream>>>(scl, cidx, cval, X, eXd, cw, H, prob, eps, out);
}

// Round 2
// 618.333 us; speedup vs baseline: 1.7538x; 1.7538x over previous
//
#include <hip/hip_runtime.h>

#define N_NODES 4096
#define M_EDGES 4096
#define NNZ_K   262144
#define NCH     4
#define DIM     128
#define KDIM    512               // NCH*DIM
#define NM      (N_NODES * M_EDGES)
#define NUM_ADD 26214             // max(1, int(0.1*NNZ))
#define NCB     2048              // coarse bins over [-1, 1]
#define CAP     65536

// ---- workspace layout (byte offsets) ----
#define EXD_OFF   0ull                 // double[M*D]      4 MB
#define AFC_OFF   4194304ull           // float[N*512]     8 MB
#define BFC_OFF   12582912ull          // float[M*512]     8 MB
#define BKT_OFF   20971520ull          // int[NNZ]         1 MB
#define CVAL_OFF  22020096ull          // double[CAP]      512 KB
#define CIDX_OFF  22544384ull          // int[CAP]         256 KB
#define CNT_OFF   22806528ull          // int[4096]        (zeroed region starts here)
#define OFFS_OFF  22822912ull          // int[4097]
#define CUR_OFF   22839300ull          // int[4096]
#define HIST_OFF  22855684ull          // int[NCB]
#define SCL_OFF   22863876ull          // int[16]  {bstar, G1, ncand}
#define ZERO_BYTES (22863940ull - CNT_OFF)

__device__ __forceinline__ int bin_c(float s) {
    int b = (int)floorf((s + 1.0f) * 1024.0f);
    return min(max(b, 0), NCB - 1);
}

__device__ __forceinline__ float st_mask(float p, float e) {
    float logit = logf(e) - logf(1.0f - e) + logf(p + 1e-8f) - logf(1.0f - p + 1e-8f);
    float soft  = 1.0f / (1.0f + expf(-2.0f * logit));   // sigmoid(logit/TEMP), TEMP=0.5
    float hard  = (soft > 0.5f) ? 1.0f : 0.0f;
    return (hard - soft) + soft;                          // straight-through forward
}

// ---- 1. per-edge counts ----
__global__ void k_count(const int* __restrict__ E, int* __restrict__ cnt) {
    int k = blockIdx.x * 256 + threadIdx.x;
    if (k < NNZ_K) atomicAdd(&cnt[E[k]], 1);
}

// ---- 2. exclusive scan over 4096 counts ----
__global__ __launch_bounds__(256) void k_scan(const int* __restrict__ cnt, int* __restrict__ offs) {
    __shared__ int part[256];
    int t = threadIdx.x;
    int loc[16]; int s = 0;
    for (int j = 0; j < 16; ++j) { loc[j] = cnt[t * 16 + j]; s += loc[j]; }
    part[t] = s;
    __syncthreads();
    if (t == 0) { int acc = 0; for (int i = 0; i < 256; ++i) { int v = part[i]; part[i] = acc; acc += v; } }
    __syncthreads();
    int acc = part[t];
    for (int j = 0; j < 16; ++j) { offs[t * 16 + j] = acc; acc += loc[j]; }
    if (t == 255) offs[4096] = acc;
}

// ---- 3. bucket fill (order nondeterministic; fixed by sort in next kernel) ----
__global__ void k_fill(const int* __restrict__ E, const int* __restrict__ offs,
                       int* __restrict__ cur, int* __restrict__ bkt) {
    int k = blockIdx.x * 256 + threadIdx.x;
    if (k < NNZ_K) {
        int e = E[k];
        int pos = atomicAdd(&cur[e], 1);
        bkt[offs[e] + pos] = k;
    }
}

// ---- 4. deterministic scatter-mean: sort bucket by k, fp64 accumulate ----
__global__ __launch_bounds__(128) void k_edge_mean(
        const int* __restrict__ Vv, const int* __restrict__ cnt,
        const int* __restrict__ offs, const int* __restrict__ bkt,
        const float* __restrict__ X, double* __restrict__ eXd) {
    __shared__ int sk[1024];
    __shared__ int sv[1024];
    int m = blockIdx.x;
    int c = cnt[m]; if (c > 1024) c = 1024;
    int off = offs[m];
    for (int t = threadIdx.x; t < c; t += 128) sk[t] = bkt[off + t];
    __syncthreads();
    for (int t = threadIdx.x; t < c; t += 128) {   // rank sort (keys distinct)
        int key = sk[t]; int r = 0;
        for (int j = 0; j < c; ++j) r += (sk[j] < key);
        sv[r] = Vv[key];
    }
    __syncthreads();
    int d = threadIdx.x;
    double s = 0.0;
    for (int j = 0; j < c; ++j) s += (double)X[sv[j] * DIM + d];
    eXd[m * DIM + d] = s / (double)(c > 1 ? c : 1);
}

// ---- 5. per-channel L2-normalized features (fp64 internal, fp32 out) ----
template <typename T>
__global__ __launch_bounds__(128) void k_fc(const T* __restrict__ in,
                                            const float* __restrict__ w,
                                            float* __restrict__ out) {
    __shared__ double red[128];
    int n = blockIdx.x, d = threadIdx.x;
    double x = (double)in[n * DIM + d];
    for (int c = 0; c < NCH; ++c) {
        double v = x * (double)w[c * DIM + d];
        red[d] = v * v;
        __syncthreads();
        for (int s = 64; s > 0; s >>= 1) { if (d < s) red[d] += red[d + s]; __syncthreads(); }
        double denom = fmax(sqrt(red[0]), 1e-12);
        __syncthreads();
        out[n * KDIM + c * DIM + d] = (float)(v / denom);
    }
}

// ---- 6. fp32 GEMM: S = 0.25 * A(N,512) * B(M,512)^T -> d_out ----
#define BKK 32
__global__ __launch_bounds__(256) void k_gemm(const float* __restrict__ A,
                                              const float* __restrict__ B,
                                              float* __restrict__ S) {
    __shared__ float As[BKK][68];
    __shared__ float Bs[BKK][68];
    int row0 = blockIdx.y * 64, col0 = blockIdx.x * 64;
    int tid = threadIdx.x;
    int tx = tid & 15, ty = tid >> 4;
    int lr = tid >> 3;            // 0..31
    int lk = (tid & 7) * 4;       // 0,4,...,28
    float acc[4][4] = {};
    for (int k0 = 0; k0 < KDIM; k0 += BKK) {
        float4 a0 = *(const float4*)&A[(size_t)(row0 + lr) * KDIM + k0 + lk];
        float4 a1 = *(const float4*)&A[(size_t)(row0 + lr + 32) * KDIM + k0 + lk];
        float4 b0 = *(const float4*)&B[(size_t)(col0 + lr) * KDIM + k0 + lk];
        float4 b1 = *(const float4*)&B[(size_t)(col0 + lr + 32) * KDIM + k0 + lk];
        __syncthreads();
        As[lk + 0][lr] = a0.x; As[lk + 1][lr] = a0.y; As[lk + 2][lr] = a0.z; As[lk + 3][lr] = a0.w;
        As[lk + 0][lr + 32] = a1.x; As[lk + 1][lr + 32] = a1.y; As[lk + 2][lr + 32] = a1.z; As[lk + 3][lr + 32] = a1.w;
        Bs[lk + 0][lr] = b0.x; Bs[lk + 1][lr] = b0.y; Bs[lk + 2][lr] = b0.z; Bs[lk + 3][lr] = b0.w;
        Bs[lk + 0][lr + 32] = b1.x; Bs[lk + 1][lr + 32] = b1.y; Bs[lk + 2][lr + 32] = b1.z; Bs[lk + 3][lr + 32] = b1.w;
        __syncthreads();
        #pragma unroll
        for (int kk = 0; kk < BKK; ++kk) {
            float4 av = *(const float4*)&As[kk][ty * 4];
            float4 bv = *(const float4*)&Bs[kk][tx * 4];
            float a4[4] = {av.x, av.y, av.z, av.w};
            float b4[4] = {bv.x, bv.y, bv.z, bv.w};
            #pragma unroll
            for (int i = 0; i < 4; ++i)
                #pragma unroll
                for (int j = 0; j < 4; ++j)
                    acc[i][j] += a4[i] * b4[j];
        }
    }
    #pragma unroll
    for (int i = 0; i < 4; ++i)
        #pragma unroll
        for (int j = 0; j < 4; ++j)
            S[(size_t)(row0 + ty * 4 + i) * M_EDGES + (col0 + tx * 4 + j)] = 0.25f * acc[i][j];
}

// ---- 7. mask existing incidences ----
__global__ void k_mask(const int* __restrict__ Vv, const int* __restrict__ E, float* __restrict__ S) {
    int k = blockIdx.x * 256 + threadIdx.x;
    if (k < NNZ_K) S[(size_t)Vv[k] * M_EDGES + E[k]] = -1e30f;
}

// ---- 8. coarse histogram, LDS-privatized (fixes the 606us atomic storm) ----
__global__ __launch_bounds__(256) void k_hist_coarse(const float4* __restrict__ S4,
                                                     int* __restrict__ hist) {
    __shared__ int h[NCB];
    for (int i = threadIdx.x; i < NCB; i += 256) h[i] = 0;
    __syncthreads();
    int stride = gridDim.x * 256;
    for (int i = blockIdx.x * 256 + threadIdx.x; i < NM / 4; i += stride) {
        float4 v = S4[i];
        float sv[4] = {v.x, v.y, v.z, v.w};
        #pragma unroll
        for (int c = 0; c < 4; ++c)
            if (sv[c] > -2.0f) atomicAdd(&h[bin_c(sv[c])], 1);
    }
    __syncthreads();
    for (int i = threadIdx.x; i < NCB; i += 256)
        if (h[i]) atomicAdd(&hist[i], h[i]);
}

// ---- 9. find cutoff bin b* and G1 = count of bins >= b*+2 ----
__global__ __launch_bounds__(256) void k_findcut(const int* __restrict__ hist, int* __restrict__ scl) {
    __shared__ int part[256];
    int t = threadIdx.x;
    int loc[8]; int s = 0;
    for (int j = 0; j < 8; ++j) { loc[j] = hist[t * 8 + j]; s += loc[j]; }
    part[t] = s;
    __syncthreads();
    if (t == 0) { int acc = 0; for (int i = 255; i >= 0; --i) { int v = part[i]; part[i] = acc; acc += v; } }
    __syncthreads();
    int run = part[t];                  // elements strictly above this chunk
    for (int j = 7; j >= 0; --j) {
        int h = loc[j];
        run += h;
        if (run >= NUM_ADD && run - h < NUM_ADD) {
            int bstar = t * 8 + j;
            int g0 = run - h;           // count in bins > bstar
            int h1 = (bstar + 1 < NCB) ? hist[bstar + 1] : 0;
            scl[0] = bstar;
            scl[1] = g0 - h1;           // G1: certainly-selected count (bins >= bstar+2)
        }
    }
}

// ---- 10. fused elementwise output + band-candidate collection ----
__global__ __launch_bounds__(256) void k_final(
        float* __restrict__ S, const float* __restrict__ H,
        const float* __restrict__ prob, const float* __restrict__ eps,
        int* __restrict__ scl, int* __restrict__ cidx) {
    size_t i = (size_t)blockIdx.x * 256 + threadIdx.x;   // over NM/4
    int bs = scl[0];
    float4 s = ((const float4*)S)[i];
    float4 h = ((const float4*)H)[i];
    float4 p = ((const float4*)prob)[i];
    float4 e = ((const float4*)eps)[i];
    float sv[4] = {s.x, s.y, s.z, s.w};
    float hv[4] = {h.x, h.y, h.z, h.w};
    float pv[4] = {p.x, p.y, p.z, p.w};
    float ev[4] = {e.x, e.y, e.z, e.w};
    float ov[4];
    #pragma unroll
    for (int c = 0; c < 4; ++c) {
        float sc = sv[c];
        bool valid = sc > -2.0f;
        int b = bin_c(sc);
        float add = (valid && b >= bs + 2) ? 1.0f : 0.0f;
        if (valid && b >= bs - 1 && b <= bs + 1) {
            int slot = atomicAdd(&scl[2], 1);
            if (slot < CAP) cidx[slot] = (int)(i * 4 + c);
        }
        ov[c] = (hv[c] + add) * st_mask(pv[c], ev[c]);
    }
    ((float4*)S)[i] = make_float4(ov[0], ov[1], ov[2], ov[3]);
}

// ---- 11. exact fp64 values for band candidates ----
__global__ __launch_bounds__(256) void k_exact(
        const int* __restrict__ scl, const int* __restrict__ cidx, double* __restrict__ cval,
        const float* __restrict__ X, const double* __restrict__ eXd, const float* __restrict__ cw) {
    int nc = scl[2]; if (nc > CAP) nc = CAP;
    for (int i = blockIdx.x * 256 + threadIdx.x; i < nc; i += 256 * 256) {
        int idx = cidx[i];
        int n = idx >> 12, m = idx & (M_EDGES - 1);
        double acc = 0.0;
        for (int c = 0; c < NCH; ++c) {
            double dn = 0.0, de = 0.0, dt = 0.0;
            for (int d = 0; d < DIM; ++d) {
                double w  = (double)cw[c * DIM + d];
                double xn = (double)X[n * DIM + d] * w;
                double xe = eXd[m * DIM + d] * w;
                dn += xn * xn; de += xe * xe; dt += xn * xe;
            }
            acc += dt / (fmax(sqrt(dn), 1e-12) * fmax(sqrt(de), 1e-12));
        }
        cval[i] = acc * 0.25;
    }
}

// ---- 12. exact rank (LDS-tiled) + write selected band elements ----
#define RTILE 2048
__global__ __launch_bounds__(256) void k_rank(
        const int* __restrict__ scl, const int* __restrict__ cidx, const double* __restrict__ cval,
        const float* __restrict__ H, const float* __restrict__ prob, const float* __restrict__ eps,
        float* __restrict__ out) {
    __shared__ double tv[RTILE];
    __shared__ int    ti[RTILE];
    int nc = scl[2]; if (nc > CAP) nc = CAP;
    if (blockIdx.x * 256 >= nc) return;
    int i = blockIdx.x * 256 + threadIdx.x;
    bool active = (i < nc);
    double v = 0.0; int idx = 0;
    if (active) { v = cval[i]; idx = cidx[i]; }
    int rank = scl[1];                   // start at G1 (certainly-selected count)
    for (int t0 = 0; t0 < nc; t0 += RTILE) {
        int tl = min(RTILE, nc - t0);
        __syncthreads();
        for (int j = threadIdx.x; j < tl; j += 256) { tv[j] = cval[t0 + j]; ti[j] = cidx[t0 + j]; }
        __syncthreads();
        if (active)
            for (int j = 0; j < tl; ++j) {
                double u = tv[j];
                rank += (u > v || (u == v && ti[j] < idx)) ? 1 : 0;
            }
    }
    if (active && rank < NUM_ADD)
        out[idx] = (H[idx] + 1.0f) * st_mask(prob[idx], eps[idx]);
}

extern "C" void kernel_launch(void* const* d_in, const int* in_sizes, int n_in,
                              void* d_out, int out_size, void* d_ws, size_t ws_size,
                              hipStream_t stream) {
    const float* X    = (const float*)d_in[0];
    const float* H    = (const float*)d_in[1];
    const int*   Vv   = (const int*)d_in[2];
    const int*   E    = (const int*)d_in[3];
    const float* prob = (const float*)d_in[4];
    const float* cw   = (const float*)d_in[5];
    const float* eps  = (const float*)d_in[6];
    float* out = (float*)d_out;
    char*  ws  = (char*)d_ws;

    double* eXd  = (double*)(ws + EXD_OFF);
    float*  Afc  = (float*)(ws + AFC_OFF);
    float*  Bfc  = (float*)(ws + BFC_OFF);
    int*    bkt  = (int*)(ws + BKT_OFF);
    double* cval = (double*)(ws + CVAL_OFF);
    int*    cidx = (int*)(ws + CIDX_OFF);
    int*    cnt  = (int*)(ws + CNT_OFF);
    int*    offs = (int*)(ws + OFFS_OFF);
    int*    cur  = (int*)(ws + CUR_OFF);
    int*    hist = (int*)(ws + HIST_OFF);
    int*    scl  = (int*)(ws + SCL_OFF);

    hipMemsetAsync(ws + CNT_OFF, 0, (size_t)ZERO_BYTES, stream);

    k_count<<<NNZ_K / 256, 256, 0, stream>>>(E, cnt);
    k_scan<<<1, 256, 0, stream>>>(cnt, offs);
    k_fill<<<NNZ_K / 256, 256, 0, stream>>>(E, offs, cur, bkt);
    k_edge_mean<<<M_EDGES, 128, 0, stream>>>(Vv, cnt, offs, bkt, X, eXd);
    k_fc<float><<<N_NODES, 128, 0, stream>>>(X, cw, Afc);
    k_fc<double><<<M_EDGES, 128, 0, stream>>>(eXd, cw, Bfc);
    dim3 gg(M_EDGES / 64, N_NODES / 64);
    k_gemm<<<gg, 256, 0, stream>>>(Afc, Bfc, out);
    k_mask<<<NNZ_K / 256, 256, 0, stream>>>(Vv, E, out);
    k_hist_coarse<<<512, 256, 0, stream>>>((const float4*)out, hist);
    k_findcut<<<1, 256, 0, stream>>>(hist, scl);
    k_final<<<NM / 4 / 256, 256, 0, stream>>>(out, H, prob, eps, scl, cidx);
    k_exact<<<256, 256, 0, stream>>>(scl, cidx, cval, X, eXd, cw);
    k_rank<<<256, 256, 0, stream>>>(scl, cidx, cval, H, prob, eps, out);
}